// Round 1
// baseline (82717.499 us; speedup 1.0000x reference)
//
#include <hip/hip_runtime.h>
#include <cfloat>
#include <cmath>

namespace {

constexpr int Bn = 64;     // batch
constexpr int Sn = 128;    // encoder seq len
constexpr int En = 512;    // embedding dim
constexpr int Hn = 1024;   // hidden dim
constexpr int Vn = 10000;  // vocab
constexpr int Tn = 144;    // 1 + STEPS output positions
constexpr int DEC = 143;   // decode steps
constexpr int ENC_CHUNK = 16;

__device__ __forceinline__ double sigd(double x) { return 1.0 / (1.0 + exp(-x)); }

// Zero the 6 state regions (h0 ping-pong, h1 ping-pong, c0, c1): 6*64*1024 doubles.
__global__ __launch_bounds__(256) void init_state(double* __restrict__ ws) {
    const size_t i = (size_t)blockIdx.x * blockDim.x + threadIdx.x;  // 0 .. 6*BH-1
    ws[i] = 0.0;
}

// Gather ENC_CHUNK encoder steps of embeddings into transposed fp32 x_t[ti][k][b].
__global__ __launch_bounds__(256) void gather_enc(
    const int* __restrict__ x, const float* __restrict__ emb,
    float* __restrict__ xt, const int t0)
{
    const int b  = (int)blockIdx.x & 63;
    const int ti = (int)blockIdx.x >> 6;
    const int token = x[b * Sn + t0 + ti];
    const float* __restrict__ er = emb + (size_t)token * En;
    float* __restrict__ xo = xt + (size_t)ti * En * 64;
    for (int k = (int)threadIdx.x; k < En; k += 256)
        xo[(size_t)k * 64 + b] = er[k];   // read coalesced; write small scatter (one-time)
}

// GEMV inner part: accumulate 4 j-rows x 4 gates over this wave's k-chunk (K/8).
// acc[jj][g] += sum_k W[g*Hn + j0+jj][k] * x[k][b]   (all fp64 FMA, f32->f64 cvt per weight)
// xcol already has +b applied. k0 = w * (K/8).
template<typename XT, int K>
__device__ __forceinline__ void gemv_part(
    double (&acc)[4][4],
    const XT* __restrict__ xcol,    // [K][64] (+b)
    const float* __restrict__ W,    // [4*Hn][K]
    const int j0, const int k0)
{
    const float4* r[4][4];
    #pragma unroll
    for (int jj = 0; jj < 4; ++jj)
        #pragma unroll
        for (int g = 0; g < 4; ++g)
            r[jj][g] = (const float4*)(W + ((size_t)g * Hn + (j0 + jj)) * K + k0);
    const XT* __restrict__ xp = xcol + (size_t)k0 * 64;
    constexpr int C = K / 8;        // this wave's k-chunk
    #pragma unroll 2
    for (int i = 0; i < C / 4; ++i) {
        const double x0 = (double)xp[(size_t)(4 * i + 0) * 64];
        const double x1 = (double)xp[(size_t)(4 * i + 1) * 64];
        const double x2 = (double)xp[(size_t)(4 * i + 2) * 64];
        const double x3 = (double)xp[(size_t)(4 * i + 3) * 64];
        #pragma unroll
        for (int jj = 0; jj < 4; ++jj)
            #pragma unroll
            for (int g = 0; g < 4; ++g) {
                const float4 wv = r[jj][g][i];   // wave-uniform 16B broadcast load
                double a = acc[jj][g];
                a = fma(x0, (double)wv.x, a);
                a = fma(x1, (double)wv.y, a);
                a = fma(x2, (double)wv.z, a);
                a = fma(x3, (double)wv.w, a);
                acc[jj][g] = a;
            }
    }
}

// One LSTM cell. State layout TRANSPOSED: h/c/x stored [k][64] so lane=b is coalesced.
// NEW geometry: block = 512 threads = 8 waves; block owns 4 j-rows (grid = Hn/4 = 256
// = 1 block/CU); waves 8-way k-split; each thread carries 16 fp64 accumulators
// (4j x 4 gates) -> 64 FMA per 16 weight-float4 loads (4x the old density, 4x less
// input-broadcast traffic). Partials reduced via 64KB LDS. All math fp64 as before.
template<typename XT, int KX>
__global__ __launch_bounds__(512, 2) void cell_kernel(
    const XT*     __restrict__ xt,    // [KX][64]
    const double* __restrict__ hin,   // [Hn][64]
    double*       __restrict__ hout,  // [Hn][64]
    double*       __restrict__ cst,   // [Hn][64]
    const float*  __restrict__ Wih,   // [4Hn][KX] rows i,f,g,o
    const float*  __restrict__ Whh,   // [4Hn][Hn]
    const float*  __restrict__ bih,
    const float*  __restrict__ bhh)
{
    __shared__ double part[8][16][64];   // [wave][jj*4+g][b] = 64 KB
    const int tid = (int)threadIdx.x;
    const int b = tid & 63;
    const int w = tid >> 6;              // 0..7
    const int j0 = (int)blockIdx.x * 4;

    double acc[4][4] = {};

    gemv_part<XT, KX>(acc, xt + b, Wih, j0, w * (KX / 8));    // x part
    gemv_part<double, Hn>(acc, hin + b, Whh, j0, w * (Hn / 8)); // h part

    #pragma unroll
    for (int jj = 0; jj < 4; ++jj)
        #pragma unroll
        for (int g = 0; g < 4; ++g)
            part[w][jj * 4 + g][b] = acc[jj][g];
    __syncthreads();

    if (tid < 256) {
        const int bb = tid & 63;
        const int jj = tid >> 6;
        const int j = j0 + jj;
        double sg[4];
        #pragma unroll
        for (int g = 0; g < 4; ++g) {
            double a = (double)bih[g * Hn + j] + (double)bhh[g * Hn + j];
            #pragma unroll
            for (int ww = 0; ww < 8; ++ww) a += part[ww][jj * 4 + g][bb];
            sg[g] = a;
        }
        const double ig = sigd(sg[0]);
        const double fg = sigd(sg[1]);
        const double gg = tanh(sg[2]);
        const double og = sigd(sg[3]);
        const size_t idx = (size_t)j * 64 + bb;
        const double cn = fg * cst[idx] + ig * gg;
        cst[idx] = cn;
        hout[idx] = og * tanh(cn);
    }
}

// logits[b, v0..v0+15]; block = 512 threads (8 waves k-splitting Hn); grid = Vn/16 = 625.
// 16 vocab rows per block (was 4): 4x less h-broadcast traffic, 64 FMA per 16 W loads.
// Writes fp32 directly into d_out at [b][t][v] (t folded into outf pointer).
__global__ __launch_bounds__(512, 2) void logits_kernel(
    const double* __restrict__ h,     // [Hn][64]
    const float*  __restrict__ Wfc,   // [Vn][Hn]
    const float*  __restrict__ bfc,
    float*        __restrict__ outf)  // d_out + t*Vn ; b stride = Tn*Vn
{
    __shared__ double part[8][16][64];   // [wave][vv][b] = 64 KB
    const int tid = (int)threadIdx.x;
    const int b = tid & 63;
    const int w = tid >> 6;
    const int v0 = (int)blockIdx.x * 16;

    double acc[16] = {};
    const int k0 = w * (Hn / 8);
    const float4* r[16];
    #pragma unroll
    for (int vv = 0; vv < 16; ++vv)
        r[vv] = (const float4*)(Wfc + (size_t)(v0 + vv) * Hn + k0);
    const double* __restrict__ hp = h + (size_t)k0 * 64 + b;
    #pragma unroll 2
    for (int i = 0; i < (Hn / 8) / 4; ++i) {    // 32 iters
        const double x0 = hp[(size_t)(4 * i + 0) * 64];
        const double x1 = hp[(size_t)(4 * i + 1) * 64];
        const double x2 = hp[(size_t)(4 * i + 2) * 64];
        const double x3 = hp[(size_t)(4 * i + 3) * 64];
        #pragma unroll
        for (int vv = 0; vv < 16; ++vv) {
            const float4 wv = r[vv][i];
            double a = acc[vv];
            a = fma(x0, (double)wv.x, a);
            a = fma(x1, (double)wv.y, a);
            a = fma(x2, (double)wv.z, a);
            a = fma(x3, (double)wv.w, a);
            acc[vv] = a;
        }
    }
    #pragma unroll
    for (int vv = 0; vv < 16; ++vv) part[w][vv][b] = acc[vv];
    __syncthreads();

    const int bb = tid & 63;
    const int vh = tid >> 6;             // 0..7 -> rows vh and vh+8
    #pragma unroll
    for (int t2 = 0; t2 < 2; ++t2) {
        const int vv = vh + t2 * 8;
        double s = (double)bfc[v0 + vv];
        #pragma unroll
        for (int ww = 0; ww < 8; ++ww) s += part[ww][vv][bb];
        outf[(size_t)bb * ((size_t)Tn * Vn) + v0 + vv] = (float)s;
    }
}

// Fused first-index argmax (matches jnp.argmax) + embedding gather into x_t[k][b].
// One block per batch row b.
template<typename T>
__global__ __launch_bounds__(256) void argmax_gather(
    const T* __restrict__ vals, const int n, const int estride, const size_t bstride,
    const float* __restrict__ emb, float* __restrict__ xt)
{
    __shared__ double sv[256];
    __shared__ int si[256];
    __shared__ int stok;
    const int tid = (int)threadIdx.x;
    const int b = (int)blockIdx.x;
    const T* __restrict__ row = vals + (size_t)b * bstride;
    double best = -DBL_MAX;
    int bi = 0x7fffffff;
    for (int k = tid; k < n; k += 256) {
        const double v = (double)row[(size_t)k * estride];
        if (v > best) { best = v; bi = k; }   // strict > keeps earliest index in-thread
    }
    sv[tid] = best; si[tid] = bi;
    __syncthreads();
    for (int s = 128; s > 0; s >>= 1) {
        if (tid < s) {
            if (sv[tid + s] > sv[tid] || (sv[tid + s] == sv[tid] && si[tid + s] < si[tid])) {
                sv[tid] = sv[tid + s];
                si[tid] = si[tid + s];
            }
        }
        __syncthreads();
    }
    if (tid == 0) stok = si[0];
    __syncthreads();
    const float* __restrict__ er = emb + (size_t)stok * En;
    for (int k = tid; k < En; k += 256)
        xt[(size_t)k * 64 + b] = er[k];
}

} // namespace

extern "C" void kernel_launch(void* const* d_in, const int* in_sizes, int n_in,
                              void* d_out, int out_size, void* d_ws, size_t ws_size,
                              hipStream_t stream)
{
    const int*   x    = (const int*)d_in[0];
    const float* emb  = (const float*)d_in[1];
    const float* Wih0 = (const float*)d_in[2];
    const float* Whh0 = (const float*)d_in[3];
    const float* bih0 = (const float*)d_in[4];
    const float* bhh0 = (const float*)d_in[5];
    const float* Wih1 = (const float*)d_in[6];
    const float* Whh1 = (const float*)d_in[7];
    const float* bih1 = (const float*)d_in[8];
    const float* bhh1 = (const float*)d_in[9];
    const float* Wfc  = (const float*)d_in[10];
    const float* bfc  = (const float*)d_in[11];
    float* out = (float*)d_out;

    // ws (doubles): h0[2][BH] | h1[2][BH] | c0[BH] | c1[BH]  then fp32 xt[ENC_CHUNK][En][64]
    double* ws = (double*)d_ws;
    const size_t BH = (size_t)Bn * Hn;   // 65536
    double* h0 = ws;
    double* h1 = ws + 2 * BH;
    double* c0 = ws + 4 * BH;
    double* c1 = ws + 5 * BH;
    float*  xt = (float*)(ws + 6 * BH);  // 16*512*64 floats = 2 MB; total ws use ~5.3 MB

    init_state<<<1536, 256, 0, stream>>>(ws);   // zeros all 6 BH regions

    int p = 0;
    // -------- encoder: 128 steps, embedding gathers chunked x16 --------
    for (int t0 = 0; t0 < Sn; t0 += ENC_CHUNK) {
        gather_enc<<<ENC_CHUNK * 64, 256, 0, stream>>>(x, emb, xt, t0);
        for (int ti = 0; ti < ENC_CHUNK; ++ti) {
            cell_kernel<float, En><<<Hn / 4, 512, 0, stream>>>(
                xt + (size_t)ti * En * 64,
                h0 + (size_t)p * BH, h0 + (size_t)(1 - p) * BH, c0,
                Wih0, Whh0, bih0, bhh0);
            cell_kernel<double, Hn><<<Hn / 4, 512, 0, stream>>>(
                h0 + (size_t)(1 - p) * BH,
                h1 + (size_t)p * BH, h1 + (size_t)(1 - p) * BH, c1,
                Wih1, Whh1, bih1, bhh1);
            p ^= 1;
        }
    }

    // first logits row (t=0) + quirk token: argmax over the raw hidden state
    logits_kernel<<<Vn / 16, 512, 0, stream>>>(h1 + (size_t)p * BH, Wfc, bfc, out);
    argmax_gather<double><<<64, 256, 0, stream>>>(
        h1 + (size_t)p * BH, Hn, 64, 1, emb, xt);   // row base h1+b, elem stride 64

    // -------- decoder: 143 steps --------
    for (int s = 0; s < DEC; ++s) {
        cell_kernel<float, En><<<Hn / 4, 512, 0, stream>>>(
            xt,
            h0 + (size_t)p * BH, h0 + (size_t)(1 - p) * BH, c0,
            Wih0, Whh0, bih0, bhh0);
        cell_kernel<double, Hn><<<Hn / 4, 512, 0, stream>>>(
            h0 + (size_t)(1 - p) * BH,
            h1 + (size_t)p * BH, h1 + (size_t)(1 - p) * BH, c1,
            Wih1, Whh1, bih1, bhh1);
        p ^= 1;
        logits_kernel<<<Vn / 16, 512, 0, stream>>>(
            h1 + (size_t)p * BH, Wfc, bfc, out + (size_t)(1 + s) * Vn);
        if (s + 1 < DEC) {
            argmax_gather<float><<<64, 256, 0, stream>>>(
                out + (size_t)(1 + s) * Vn, Vn, 1, (size_t)Tn * Vn, emb, xt);
        }
    }

    (void)in_sizes; (void)n_in; (void)out_size; (void)ws_size;
}